// Round 1
// baseline (700.025 us; speedup 1.0000x reference)
//
#include <hip/hip_runtime.h>
#include <math.h>

typedef unsigned short u16;
typedef __bf16 bf16x8_t __attribute__((ext_vector_type(8)));
typedef float f32x4_t __attribute__((ext_vector_type(4)));

#define B_  2
#define S_  2048
#define D_  2048
#define H_  16
#define G_  4
#define DH_ 128

#define NEG_SENTINEL (-3.0e38f)
// 1/sqrt(128) * log2(e): folded into q at rope time so softmax uses exp2 directly
#define Q_SCALE (0.08838834764831843f * 1.4426950408889634f)

__device__ __forceinline__ float b2f(u16 u) {
    union { unsigned int i; float f; } v; v.i = ((unsigned int)u) << 16; return v.f;
}
__device__ __forceinline__ u16 f2b(float f) {
    union { float f; unsigned int i; } v; v.f = f;
    unsigned int r = v.i + 0x7fffu + ((v.i >> 16) & 1u);  // RNE
    return (u16)(r >> 16);
}
__device__ __forceinline__ void stc(u16* p, float v)   { *p = f2b(v); }
__device__ __forceinline__ void stc(float* p, float v) { *p = v; }

// XOR-swizzle (T2): permutes 16B chunks within a row's 8-chunk stripe.
// elem_index ^= kxor(row). Extra (row>>3)&1 bit de-conflicts scalar P writes.
__device__ __forceinline__ int kxor(int r) {
    return (((r) & 7) ^ (((r) >> 3) & 1)) << 3;
}

// ---------------------------------------------------------------------------
// Cast f32 -> bf16, 8 elems/thread.
// ---------------------------------------------------------------------------
__global__ __launch_bounds__(256) void cast_x(
    const float* __restrict__ in, u16* __restrict__ out) {
    int i = (blockIdx.x * 256 + threadIdx.x) * 8;
    float4 a = *(const float4*)(in + i);
    float4 b = *(const float4*)(in + i + 4);
    u16 o[8] = {f2b(a.x), f2b(a.y), f2b(a.z), f2b(a.w),
                f2b(b.x), f2b(b.y), f2b(b.z), f2b(b.w)};
    *(uint4*)(out + i) = *(uint4*)o;
}

// ---------------------------------------------------------------------------
// Transpose + cast: in f32 [R][C] -> out bf16 [C][R]. grid=(C/32, R/32)
// ---------------------------------------------------------------------------
__global__ __launch_bounds__(256) void transpose_f32_bf16(
    const float* __restrict__ in, u16* __restrict__ out, int R, int C) {
    __shared__ u16 t[32][33];
    const int c0 = blockIdx.x * 32, r0 = blockIdx.y * 32;
    const int j = threadIdx.x & 31, i = threadIdx.x >> 5;  // i in 0..7
#pragma unroll
    for (int p = 0; p < 4; ++p)
        t[i + 8 * p][j] = f2b(in[(size_t)(r0 + i + 8 * p) * C + c0 + j]);
    __syncthreads();
#pragma unroll
    for (int p = 0; p < 4; ++p)
        out[(size_t)(c0 + i + 8 * p) * R + r0 + j] = t[j][i + 8 * p];
}

// ---------------------------------------------------------------------------
// NT GEMM: C[M][N] = A[M][K] * BT[N][K]^T (bf16 in, OT out, f32 acc)
// block = 256 (4 waves), tile 128x128, BK=64. grid=(N/128, M/128)
// ---------------------------------------------------------------------------
template <typename OT>
__global__ __launch_bounds__(256) void gemm_nt(
    const u16* __restrict__ A, const u16* __restrict__ BT, OT* __restrict__ C,
    int M, int N, int K) {
    __shared__ __align__(16) u16 As[128 * 72];
    __shared__ __align__(16) u16 Bs[128 * 72];
    const int tid  = threadIdx.x;
    const int lane = tid & 63;
    const int wave = tid >> 6;
    const int wm = wave >> 1, wn = wave & 1;
    const int quad = lane >> 4, l16 = lane & 15;
    const int m0 = blockIdx.y * 128, n0 = blockIdx.x * 128;

    f32x4_t acc[4][4] = {};

    for (int k0 = 0; k0 < K; k0 += 64) {
#pragma unroll
        for (int c = tid; c < 1024; c += 256) {
            int row = c >> 3, cc = (c & 7) << 3;
            *(uint4*)(&As[row * 72 + cc]) =
                *(const uint4*)(A + (size_t)(m0 + row) * K + k0 + cc);
            *(uint4*)(&Bs[row * 72 + cc]) =
                *(const uint4*)(BT + (size_t)(n0 + row) * K + k0 + cc);
        }
        __syncthreads();
#pragma unroll
        for (int ks = 0; ks < 2; ++ks) {
            const int koff = ks * 32 + quad * 8;
            bf16x8_t a[4], b[4];
#pragma unroll
            for (int mt = 0; mt < 4; ++mt)
                a[mt] = *(const bf16x8_t*)(&As[(wm * 64 + mt * 16 + l16) * 72 + koff]);
#pragma unroll
            for (int nt = 0; nt < 4; ++nt)
                b[nt] = *(const bf16x8_t*)(&Bs[(wn * 64 + nt * 16 + l16) * 72 + koff]);
#pragma unroll
            for (int mt = 0; mt < 4; ++mt)
#pragma unroll
                for (int nt = 0; nt < 4; ++nt)
                    acc[mt][nt] = __builtin_amdgcn_mfma_f32_16x16x32_bf16(
                        a[mt], b[nt], acc[mt][nt], 0, 0, 0);
        }
        __syncthreads();
    }
#pragma unroll
    for (int mt = 0; mt < 4; ++mt)
#pragma unroll
        for (int nt = 0; nt < 4; ++nt)
#pragma unroll
            for (int r = 0; r < 4; ++r) {
                int m = m0 + wm * 64 + mt * 16 + quad * 4 + r;
                int n = n0 + wn * 64 + nt * 16 + l16;
                stc(C + (size_t)m * N + n, acc[mt][nt][r]);
            }
}

// ---------------------------------------------------------------------------
// RoPE on q in-place (bf16), folding Q_SCALE (softmax scale * log2e) into q.
// q layout [B][S][H][DH].
// ---------------------------------------------------------------------------
__global__ __launch_bounds__(256) void rope_q(u16* q) {
    int idx = blockIdx.x * 256 + threadIdx.x;
    int d = idx & 63;
    int t = idx >> 6;
    int h = t & 15; t >>= 4;
    int s = t & 2047;
    int b = t >> 11;
    size_t base = ((size_t)(b * S_ + s) * H_ + h) * DH_;
    float x1 = b2f(q[base + d]), x2 = b2f(q[base + d + 64]);
    float inv = exp2f(-(float)d * (13.287712379549449f / 64.f));  // 10000^(-d/64)
    float ang = (float)s * inv, sn, cs;
    sincosf(ang, &sn, &cs);
    q[base + d]      = f2b((x1 * cs - x2 * sn) * Q_SCALE);
    q[base + d + 64] = f2b((x2 * cs + x1 * sn) * Q_SCALE);
}

// ---------------------------------------------------------------------------
// RoPE on k: kvraw bf16 [B*S][1024] (cols 0..511 = k) ->
//   kc f32 [B][G][S][DH] (output) and kb bf16 same layout (for MFMA)
// ---------------------------------------------------------------------------
__global__ __launch_bounds__(256) void k_prep(
    const u16* __restrict__ kvraw, float* __restrict__ kc, u16* __restrict__ kb) {
    int idx = blockIdx.x * 256 + threadIdx.x;
    int d = idx & 63;
    int t = idx >> 6;
    int g = t & 3; t >>= 2;
    int s = t & 2047;
    int b = t >> 11;
    const u16* src = kvraw + (size_t)(b * S_ + s) * 1024 + g * DH_;
    float x1 = b2f(src[d]), x2 = b2f(src[d + 64]);
    float inv = exp2f(-(float)d * (13.287712379549449f / 64.f));
    float ang = (float)s * inv, sn, cs;
    sincosf(ang, &sn, &cs);
    float r1 = x1 * cs - x2 * sn;
    float r2 = x2 * cs + x1 * sn;
    size_t o = ((size_t)(b * G_ + g) * S_ + s) * DH_;
    kc[o + d]      = r1;
    kc[o + d + 64] = r2;
    kb[o + d]      = f2b(r1);
    kb[o + d + 64] = f2b(r2);
}

// ---------------------------------------------------------------------------
// v: emit v_cache f32 [B][G][S][DH] and v^T bf16 [B][G][DH][S]
// grid=(S/32, DH/32, B*G), block=256
// ---------------------------------------------------------------------------
__global__ __launch_bounds__(256) void v_prep(
    const u16* __restrict__ kvraw, float* __restrict__ vc, u16* __restrict__ vt) {
    __shared__ u16 t[32][33];
    const int s0 = blockIdx.x * 32, d0 = blockIdx.y * 32;
    const int bg = blockIdx.z, b = bg >> 2, g = bg & 3;
    const int j = threadIdx.x & 31, i = threadIdx.x >> 5;
#pragma unroll
    for (int p = 0; p < 4; ++p) {
        int s = s0 + i + 8 * p;
        u16 v = kvraw[(size_t)(b * S_ + s) * 1024 + 512 + g * DH_ + d0 + j];
        t[i + 8 * p][j] = v;
        vc[((size_t)bg * S_ + s) * DH_ + d0 + j] = b2f(v);
    }
    __syncthreads();
#pragma unroll
    for (int p = 0; p < 4; ++p)
        vt[((size_t)bg * DH_ + d0 + i + 8 * p) * S_ + s0 + j] = t[j][i + 8 * p];
}

// ---------------------------------------------------------------------------
// Flash attention v4, causal, one 64-row q-tile per block, 4 blocks/CU.
// grid=(32, H, B), block=256 (4 waves).
// Occupancy: LDS is exactly 40960 B (XOR-swizzled, no padding) so 4 blocks
// co-reside per CU (160 KiB), doubling resident waves vs the paired-tile
// version (was 2 blocks/CU, grid-limited).
// Causal balance: blockIdx.x is mapped through px = odd? 31-(x>>1) : x>>1,
// then flipped by (h&8), so co-resident blocks on a CU carry complementary
// tiles {t, 31-t} under either XCD-round-robin ({x,y+-8,z} co-CU) or
// sequential fill (consecutive x co-CU) -> uniform ~66 kv-iters per CU.
// K/V staged in LDS via register-prefetch pipeline; q pre-scaled by Q_SCALE
// so softmax is pure exp2.
// ---------------------------------------------------------------------------
__global__ __launch_bounds__(256, 4) void flash_attn(
    const u16* __restrict__ q, const u16* __restrict__ kb,
    const u16* __restrict__ vt, u16* __restrict__ ctx) {
    __shared__ __align__(16) u16 Ks[64 * 128];    // [kv 64][d 128], swizzled
    __shared__ __align__(16) u16 Vs[128 * 64];    // [d 128][kv 64], swizzled
    __shared__ __align__(16) u16 Ps[4][16 * 64];  // per-wave P tile, swizzled

    const int tid  = threadIdx.x;
    const int lane = tid & 63;
    const int wave = tid >> 6;
    const int quad = lane >> 4, l16 = lane & 15;
    const int h = blockIdx.y, b = blockIdx.z;
    const int g = h >> 2;  // H/G = 4
    const u16* Kp = kb + (size_t)(b * G_ + g) * S_ * DH_;
    const u16* Vt = vt + (size_t)(b * G_ + g) * DH_ * S_;

    // balanced tile mapping (see header comment)
    const int px = (blockIdx.x & 1) ? (31 - (int)(blockIdx.x >> 1))
                                    : (int)(blockIdx.x >> 1);
    const int tile = (h & 8) ? (31 - px) : px;
    const int t0 = tile * 64;
    const int q0w = t0 + wave * 16;
    const int kvend = t0 + 64;

    // staging chunk coords (4 chunks of 16B per thread for each of K,V)
    int krow[4], kcol[4], vrow[4], vcol[4];
#pragma unroll
    for (int i = 0; i < 4; ++i) {
        int c = tid + 256 * i;
        krow[i] = c >> 4; kcol[i] = (c & 15) << 3;
        vrow[i] = c >> 3; vcol[i] = (c & 7) << 3;
    }
    const int xr = kxor(l16);  // row-swizzle for all frag reads (row%16 = l16)

    // Q fragments: A-layout [m=lane&15][k=quad*8+j]
    bf16x8_t qf[4];
#pragma unroll
    for (int kt = 0; kt < 4; ++kt)
        qf[kt] = *(const bf16x8_t*)(
            q + ((size_t)(b * S_ + q0w + l16) * H_ + h) * DH_ + kt * 32 + quad * 8);

    f32x4_t o[8] = {};
    float m_i[4], l_i[4];
#pragma unroll
    for (int r = 0; r < 4; ++r) { m_i[r] = NEG_SENTINEL; l_i[r] = 0.f; }

    // preload kv-tile 0
    uint4 kreg[4], vreg[4];
#pragma unroll
    for (int i = 0; i < 4; ++i) {
        kreg[i] = *(const uint4*)(Kp + (size_t)krow[i] * DH_ + kcol[i]);
        vreg[i] = *(const uint4*)(Vt + (size_t)vrow[i] * S_ + vcol[i]);
    }

    for (int kv0 = 0; kv0 < kvend; kv0 += 64) {
        __syncthreads();  // previous compute done reading Ks/Vs
#pragma unroll
        for (int i = 0; i < 4; ++i) {
            *(uint4*)(&Ks[krow[i] * 128 + (kcol[i] ^ kxor(krow[i]))]) = kreg[i];
            *(uint4*)(&Vs[vrow[i] * 64 + (vcol[i] ^ kxor(vrow[i]))]) = vreg[i];
        }
        if (kv0 + 64 < kvend) {  // prefetch next kv-tile into regs
            int nx = kv0 + 64;
#pragma unroll
            for (int i = 0; i < 4; ++i) {
                kreg[i] = *(const uint4*)(Kp + (size_t)(nx + krow[i]) * DH_ + kcol[i]);
                vreg[i] = *(const uint4*)(Vt + (size_t)vrow[i] * S_ + nx + vcol[i]);
            }
        }
        __syncthreads();  // Ks/Vs visible

        // S = q-scaled Q K^T  (1 m-tile x 4 n-tiles, K=128)
        // (kv0 <= q0w+15 always holds: kv0 <= t0 <= q0w)
        f32x4_t s[4] = {};
#pragma unroll
        for (int kt = 0; kt < 4; ++kt) {
            bf16x8_t kbf[4];
#pragma unroll
            for (int nt = 0; nt < 4; ++nt)
                kbf[nt] = *(const bf16x8_t*)(
                    &Ks[(nt * 16 + l16) * 128 + ((kt * 32 + quad * 8) ^ xr)]);
#pragma unroll
            for (int nt = 0; nt < 4; ++nt)
                s[nt] = __builtin_amdgcn_mfma_f32_16x16x32_bf16(
                    qf[kt], kbf[nt], s[nt], 0, 0, 0);
        }
        // causal mask (diagonal tile only)
        if (kv0 + 63 > q0w) {
#pragma unroll
            for (int nt = 0; nt < 4; ++nt)
#pragma unroll
                for (int r = 0; r < 4; ++r) {
                    int row = q0w + quad * 4 + r;
                    int col = kv0 + nt * 16 + l16;
                    if (col > row) s[nt][r] = NEG_SENTINEL;
                }
        }
        // online softmax (no clamps needed: args always <= 0; masked
        // entries give exp2(-3e38) = +0; no row is ever fully masked)
#pragma unroll
        for (int r = 0; r < 4; ++r) {
            float mx = fmaxf(fmaxf(s[0][r], s[1][r]),
                             fmaxf(s[2][r], s[3][r]));
#pragma unroll
            for (int off = 8; off >= 1; off >>= 1)
                mx = fmaxf(mx, __shfl_xor(mx, off));
            float mnew  = fmaxf(m_i[r], mx);
            float alpha = exp2f(m_i[r] - mnew);
            m_i[r] = mnew;
            float rs = 0.f;
#pragma unroll
            for (int nt = 0; nt < 4; ++nt) {
                float p = exp2f(s[nt][r] - mnew);
                s[nt][r] = p;
                rs += p;
            }
#pragma unroll
            for (int off = 8; off >= 1; off >>= 1)
                rs += __shfl_xor(rs, off);
            l_i[r] = l_i[r] * alpha + rs;
#pragma unroll
            for (int nt = 0; nt < 8; ++nt) o[nt][r] *= alpha;
        }
        // P: C/D layout -> per-wave LDS (swizzled) -> A-operand layout
#pragma unroll
        for (int nt = 0; nt < 4; ++nt)
#pragma unroll
            for (int r = 0; r < 4; ++r)
                Ps[wave][(quad * 4 + r) * 64 +
                         ((nt * 16 + l16) ^ kxor(quad * 4 + r))] = f2b(s[nt][r]);
        // O += P V
#pragma unroll
        for (int ks = 0; ks < 2; ++ks) {
            bf16x8_t pa = *(const bf16x8_t*)(
                &Ps[wave][l16 * 64 + ((ks * 32 + quad * 8) ^ xr)]);
#pragma unroll
            for (int nt = 0; nt < 8; ++nt) {
                bf16x8_t vb = *(const bf16x8_t*)(
                    &Vs[(nt * 16 + l16) * 64 + ((ks * 32 + quad * 8) ^ xr)]);
                o[nt] = __builtin_amdgcn_mfma_f32_16x16x32_bf16(
                    pa, vb, o[nt], 0, 0, 0);
            }
        }
    }
    // epilogue
#pragma unroll
    for (int r = 0; r < 4; ++r) {
        float inv = 1.f / l_i[r];
        int s_idx = q0w + quad * 4 + r;
#pragma unroll
        for (int nt = 0; nt < 8; ++nt)
            ctx[((size_t)(b * S_ + s_idx) * H_ + h) * DH_ + nt * 16 + l16] =
                f2b(o[nt][r] * inv);
    }
}

// ---------------------------------------------------------------------------
extern "C" void kernel_launch(void* const* d_in, const int* in_sizes, int n_in,
                              void* d_out, int out_size, void* d_ws, size_t ws_size,
                              hipStream_t stream) {
    const float* x  = (const float*)d_in[0];
    const float* Wq = (const float*)d_in[1];
    const float* Wk = (const float*)d_in[2];
    const float* Wv = (const float*)d_in[3];
    const float* Wo = (const float*)d_in[4];
    // d_in[5] = mask (unused; causal computed analytically)

    float* out    = (float*)d_out;                           // [B][S][H*DH]  8,388,608 f32
    float* kc_out = out + (size_t)B_ * S_ * H_ * DH_;        // [B][G][S][DH] 2,097,152 f32
    float* vc_out = kc_out + (size_t)B_ * G_ * S_ * DH_;     // [B][G][S][DH] 2,097,152 f32

    // Borrow `out` f32 region (= 16M u16) as early scratch; both buffers are
    // dead before the final gemm writes `out` (single stream, serialized).
    u16* outw = (u16*)d_out;
    u16* xb   = outw;             // 8M u16, live phases 1-2 (x cast to bf16)
    u16* qraw = outw + 8388608;   // 8M u16, live phases 2-4

    // Workspace: 16M u16 = 32 MiB, phase-safe overlays
    u16* ws    = (u16*)d_ws;
    u16* WqT   = ws;              // 4M, phases 1-2
    u16* WoT   = ws;              // 4M, phases 3-5 (transposed after q-gemm)
    u16* WkvT  = ws + 4194304;    // 2M, phases 1-2
    u16* kb    = ws + 4194304;    // 2M, phases 3-4
    u16* vt    = ws + 6291456;    // 2M, phases 3-4
    u16* kvraw = ws + 8388608;    // 4M, phases 2-3
    u16* ctx   = ws + 8388608;    // 8M, phases 4-5

    dim3 blk(256);
    // phase 1: casts + W transposes
    cast_x<<<dim3(4096), blk, 0, stream>>>(x, xb);
    transpose_f32_bf16<<<dim3(64, 64), blk, 0, stream>>>(Wq, WqT, 2048, 2048);
    transpose_f32_bf16<<<dim3(16, 64), blk, 0, stream>>>(Wk, WkvT, 2048, 512);
    transpose_f32_bf16<<<dim3(16, 64), blk, 0, stream>>>(Wv, WkvT + (size_t)512 * 2048, 2048, 512);

    // phase 2: projections
    gemm_nt<u16><<<dim3(16, 32), blk, 0, stream>>>(xb, WqT, qraw, 4096, 2048, 2048);
    gemm_nt<u16><<<dim3(8, 32),  blk, 0, stream>>>(xb, WkvT, kvraw, 4096, 1024, 2048);

    // phase 3: RoPE + cache outputs (+ Wo transpose into WqT's slot)
    transpose_f32_bf16<<<dim3(64, 64), blk, 0, stream>>>(Wo, WoT, 2048, 2048);
    rope_q<<<dim3(16384), blk, 0, stream>>>(qraw);
    k_prep<<<dim3(4096),  blk, 0, stream>>>(kvraw, kc_out, kb);
    v_prep<<<dim3(64, 4, 8), blk, 0, stream>>>(kvraw, vc_out, vt);

    // phase 4: attention (one tile/block, 4 blocks/CU, balanced mapping)
    flash_attn<<<dim3(32, 16, 2), blk, 0, stream>>>(qraw, kb, vt, ctx);

    // phase 5: output projection (f32 out)
    gemm_nt<float><<<dim3(16, 32), blk, 0, stream>>>(ctx, WoT, out, 4096, 2048, 2048);
}

// Round 2
// 682.811 us; speedup vs baseline: 1.0252x; 1.0252x over previous
//
#include <hip/hip_runtime.h>
#include <math.h>

typedef unsigned short u16;
typedef __bf16 bf16x8_t __attribute__((ext_vector_type(8)));
typedef float f32x4_t __attribute__((ext_vector_type(4)));

#define B_  2
#define S_  2048
#define D_  2048
#define H_  16
#define G_  4
#define DH_ 128

#define NEG_SENTINEL (-3.0e38f)
// 1/sqrt(128) * log2(e): folded into q at rope time so softmax uses exp2 directly
#define Q_SCALE (0.08838834764831843f * 1.4426950408889634f)

__device__ __forceinline__ float b2f(u16 u) {
    union { unsigned int i; float f; } v; v.i = ((unsigned int)u) << 16; return v.f;
}
__device__ __forceinline__ u16 f2b(float f) {
    union { float f; unsigned int i; } v; v.f = f;
    unsigned int r = v.i + 0x7fffu + ((v.i >> 16) & 1u);  // RNE
    return (u16)(r >> 16);
}
__device__ __forceinline__ void stc(u16* p, float v)   { *p = f2b(v); }
__device__ __forceinline__ void stc(float* p, float v) { *p = v; }

// XOR-swizzle (T2): permutes 16B chunks within a row's 8-chunk stripe.
// elem_index ^= kxor(row). Extra (row>>3)&1 bit de-conflicts scalar P writes.
__device__ __forceinline__ int kxor(int r) {
    return (((r) & 7) ^ (((r) >> 3) & 1)) << 3;
}

// ---------------------------------------------------------------------------
// Cast f32 -> bf16, 8 elems/thread.
// ---------------------------------------------------------------------------
__global__ __launch_bounds__(256) void cast_x(
    const float* __restrict__ in, u16* __restrict__ out) {
    int i = (blockIdx.x * 256 + threadIdx.x) * 8;
    float4 a = *(const float4*)(in + i);
    float4 b = *(const float4*)(in + i + 4);
    u16 o[8] = {f2b(a.x), f2b(a.y), f2b(a.z), f2b(a.w),
                f2b(b.x), f2b(b.y), f2b(b.z), f2b(b.w)};
    *(uint4*)(out + i) = *(uint4*)o;
}

// ---------------------------------------------------------------------------
// Transpose + cast: in f32 [R][C] -> out bf16 [C][R]. grid=(C/32, R/32)
// ---------------------------------------------------------------------------
__global__ __launch_bounds__(256) void transpose_f32_bf16(
    const float* __restrict__ in, u16* __restrict__ out, int R, int C) {
    __shared__ u16 t[32][33];
    const int c0 = blockIdx.x * 32, r0 = blockIdx.y * 32;
    const int j = threadIdx.x & 31, i = threadIdx.x >> 5;  // i in 0..7
#pragma unroll
    for (int p = 0; p < 4; ++p)
        t[i + 8 * p][j] = f2b(in[(size_t)(r0 + i + 8 * p) * C + c0 + j]);
    __syncthreads();
#pragma unroll
    for (int p = 0; p < 4; ++p)
        out[(size_t)(c0 + i + 8 * p) * R + r0 + j] = t[j][i + 8 * p];
}

// ---------------------------------------------------------------------------
// NT GEMM: C[M][N] = A[M][K] * BT[N][K]^T (bf16 in, OT out, f32 acc)
// block = 256 (4 waves), tile 128x128, BK=64. grid=(N/128, M/128)
// ---------------------------------------------------------------------------
template <typename OT>
__global__ __launch_bounds__(256) void gemm_nt(
    const u16* __restrict__ A, const u16* __restrict__ BT, OT* __restrict__ C,
    int M, int N, int K) {
    __shared__ __align__(16) u16 As[128 * 72];
    __shared__ __align__(16) u16 Bs[128 * 72];
    const int tid  = threadIdx.x;
    const int lane = tid & 63;
    const int wave = tid >> 6;
    const int wm = wave >> 1, wn = wave & 1;
    const int quad = lane >> 4, l16 = lane & 15;
    const int m0 = blockIdx.y * 128, n0 = blockIdx.x * 128;

    f32x4_t acc[4][4] = {};

    for (int k0 = 0; k0 < K; k0 += 64) {
#pragma unroll
        for (int c = tid; c < 1024; c += 256) {
            int row = c >> 3, cc = (c & 7) << 3;
            *(uint4*)(&As[row * 72 + cc]) =
                *(const uint4*)(A + (size_t)(m0 + row) * K + k0 + cc);
            *(uint4*)(&Bs[row * 72 + cc]) =
                *(const uint4*)(BT + (size_t)(n0 + row) * K + k0 + cc);
        }
        __syncthreads();
#pragma unroll
        for (int ks = 0; ks < 2; ++ks) {
            const int koff = ks * 32 + quad * 8;
            bf16x8_t a[4], b[4];
#pragma unroll
            for (int mt = 0; mt < 4; ++mt)
                a[mt] = *(const bf16x8_t*)(&As[(wm * 64 + mt * 16 + l16) * 72 + koff]);
#pragma unroll
            for (int nt = 0; nt < 4; ++nt)
                b[nt] = *(const bf16x8_t*)(&Bs[(wn * 64 + nt * 16 + l16) * 72 + koff]);
#pragma unroll
            for (int mt = 0; mt < 4; ++mt)
#pragma unroll
                for (int nt = 0; nt < 4; ++nt)
                    acc[mt][nt] = __builtin_amdgcn_mfma_f32_16x16x32_bf16(
                        a[mt], b[nt], acc[mt][nt], 0, 0, 0);
        }
        __syncthreads();
    }
#pragma unroll
    for (int mt = 0; mt < 4; ++mt)
#pragma unroll
        for (int nt = 0; nt < 4; ++nt)
#pragma unroll
            for (int r = 0; r < 4; ++r) {
                int m = m0 + wm * 64 + mt * 16 + quad * 4 + r;
                int n = n0 + wn * 64 + nt * 16 + l16;
                stc(C + (size_t)m * N + n, acc[mt][nt][r]);
            }
}

// ---------------------------------------------------------------------------
// RoPE on q in-place (bf16), folding Q_SCALE (softmax scale * log2e) into q.
// q layout [B][S][H][DH].
// ---------------------------------------------------------------------------
__global__ __launch_bounds__(256) void rope_q(u16* q) {
    int idx = blockIdx.x * 256 + threadIdx.x;
    int d = idx & 63;
    int t = idx >> 6;
    int h = t & 15; t >>= 4;
    int s = t & 2047;
    int b = t >> 11;
    size_t base = ((size_t)(b * S_ + s) * H_ + h) * DH_;
    float x1 = b2f(q[base + d]), x2 = b2f(q[base + d + 64]);
    float inv = exp2f(-(float)d * (13.287712379549449f / 64.f));  // 10000^(-d/64)
    float ang = (float)s * inv, sn, cs;
    sincosf(ang, &sn, &cs);
    q[base + d]      = f2b((x1 * cs - x2 * sn) * Q_SCALE);
    q[base + d + 64] = f2b((x2 * cs + x1 * sn) * Q_SCALE);
}

// ---------------------------------------------------------------------------
// RoPE on k: kvraw bf16 [B*S][1024] (cols 0..511 = k) ->
//   kc f32 [B][G][S][DH] (output) and kb bf16 same layout (for MFMA)
// ---------------------------------------------------------------------------
__global__ __launch_bounds__(256) void k_prep(
    const u16* __restrict__ kvraw, float* __restrict__ kc, u16* __restrict__ kb) {
    int idx = blockIdx.x * 256 + threadIdx.x;
    int d = idx & 63;
    int t = idx >> 6;
    int g = t & 3; t >>= 2;
    int s = t & 2047;
    int b = t >> 11;
    const u16* src = kvraw + (size_t)(b * S_ + s) * 1024 + g * DH_;
    float x1 = b2f(src[d]), x2 = b2f(src[d + 64]);
    float inv = exp2f(-(float)d * (13.287712379549449f / 64.f));
    float ang = (float)s * inv, sn, cs;
    sincosf(ang, &sn, &cs);
    float r1 = x1 * cs - x2 * sn;
    float r2 = x2 * cs + x1 * sn;
    size_t o = ((size_t)(b * G_ + g) * S_ + s) * DH_;
    kc[o + d]      = r1;
    kc[o + d + 64] = r2;
    kb[o + d]      = f2b(r1);
    kb[o + d + 64] = f2b(r2);
}

// ---------------------------------------------------------------------------
// v: emit v_cache f32 [B][G][S][DH] and v^T bf16 [B][G][DH][S]
// grid=(S/32, DH/32, B*G), block=256
// ---------------------------------------------------------------------------
__global__ __launch_bounds__(256) void v_prep(
    const u16* __restrict__ kvraw, float* __restrict__ vc, u16* __restrict__ vt) {
    __shared__ u16 t[32][33];
    const int s0 = blockIdx.x * 32, d0 = blockIdx.y * 32;
    const int bg = blockIdx.z, b = bg >> 2, g = bg & 3;
    const int j = threadIdx.x & 31, i = threadIdx.x >> 5;
#pragma unroll
    for (int p = 0; p < 4; ++p) {
        int s = s0 + i + 8 * p;
        u16 v = kvraw[(size_t)(b * S_ + s) * 1024 + 512 + g * DH_ + d0 + j];
        t[i + 8 * p][j] = v;
        vc[((size_t)bg * S_ + s) * DH_ + d0 + j] = b2f(v);
    }
    __syncthreads();
#pragma unroll
    for (int p = 0; p < 4; ++p)
        vt[((size_t)bg * DH_ + d0 + i + 8 * p) * S_ + s0 + j] = t[j][i + 8 * p];
}

// ---------------------------------------------------------------------------
// Flash attention v5: causal, one 64-row q-tile per block, XCD-confined KV.
// grid=(1024), block=256 (4 waves), 4 blocks/CU (LDS 40960 B x4 = 160 KiB).
//
// Block decode (assumes XCD = linear_id % 8, the HK/m157 round-robin):
//   bg = id & 7          -> each XCD owns exactly ONE (b,g): its K+V working
//                           set is 1 MB << 4 MB L2 -> KV reads are L2-hits
//                           regardless of inter-block drift (the R1 failure
//                           mode: drift broke lockstep sharing, FETCH x4.3).
//   j  = id >> 3 (0..127); hh = j>>5 (head-in-group), tr = j&31,
//   tile = (hh&1) ? 31-tr : tr  -> co-resident blocks {j, j+32, j+64, j+96}
//                           on a CU carry tiles {t,31-t,t,31-t} = 66 kv-iters
//                           per CU: balanced under breadth-first fill.
// K/V staged in LDS (XOR-swizzled, conflict-free b128 reads) with 1-deep
// register prefetch; q pre-scaled by Q_SCALE so softmax is pure exp2.
// ---------------------------------------------------------------------------
__global__ __launch_bounds__(256, 4) void flash_attn(
    const u16* __restrict__ q, const u16* __restrict__ kb,
    const u16* __restrict__ vt, u16* __restrict__ ctx) {
    __shared__ __align__(16) u16 Ks[64 * 128];    // [kv 64][d 128], swizzled
    __shared__ __align__(16) u16 Vs[128 * 64];    // [d 128][kv 64], swizzled
    __shared__ __align__(16) u16 Ps[4][16 * 64];  // per-wave P tile, swizzled

    const int tid  = threadIdx.x;
    const int lane = tid & 63;
    const int wave = tid >> 6;
    const int quad = lane >> 4, l16 = lane & 15;

    // XCD-confined decode (see header comment)
    const int id = blockIdx.x;
    const int bg = id & 7, b = bg >> 2, g = bg & 3;
    const int j  = id >> 3;
    const int hh = j >> 5, tr = j & 31;
    const int tile = (hh & 1) ? (31 - tr) : tr;
    const int h = g * 4 + hh;

    const u16* Kp = kb + (size_t)bg * S_ * DH_;
    const u16* Vt = vt + (size_t)bg * DH_ * S_;

    const int t0 = tile * 64;
    const int q0w = t0 + wave * 16;
    const int kvend = t0 + 64;

    // staging chunk coords (4 chunks of 16B per thread for each of K,V)
    int krow[4], kcol[4], vrow[4], vcol[4];
#pragma unroll
    for (int i = 0; i < 4; ++i) {
        int c = tid + 256 * i;
        krow[i] = c >> 4; kcol[i] = (c & 15) << 3;
        vrow[i] = c >> 3; vcol[i] = (c & 7) << 3;
    }
    const int xr = kxor(l16);  // row-swizzle for all frag reads (row%16 = l16)

    // Q fragments: A-layout [m=lane&15][k=quad*8+j]
    bf16x8_t qf[4];
#pragma unroll
    for (int kt = 0; kt < 4; ++kt)
        qf[kt] = *(const bf16x8_t*)(
            q + ((size_t)(b * S_ + q0w + l16) * H_ + h) * DH_ + kt * 32 + quad * 8);

    f32x4_t o[8] = {};
    float m_i[4], l_i[4];
#pragma unroll
    for (int r = 0; r < 4; ++r) { m_i[r] = NEG_SENTINEL; l_i[r] = 0.f; }

    // preload kv-tile 0
    uint4 kreg[4], vreg[4];
#pragma unroll
    for (int i = 0; i < 4; ++i) {
        kreg[i] = *(const uint4*)(Kp + (size_t)krow[i] * DH_ + kcol[i]);
        vreg[i] = *(const uint4*)(Vt + (size_t)vrow[i] * S_ + vcol[i]);
    }

    for (int kv0 = 0; kv0 < kvend; kv0 += 64) {
        __syncthreads();  // previous compute done reading Ks/Vs
#pragma unroll
        for (int i = 0; i < 4; ++i) {
            *(uint4*)(&Ks[krow[i] * 128 + (kcol[i] ^ kxor(krow[i]))]) = kreg[i];
            *(uint4*)(&Vs[vrow[i] * 64 + (vcol[i] ^ kxor(vrow[i]))]) = vreg[i];
        }
        if (kv0 + 64 < kvend) {  // prefetch next kv-tile into regs
            int nx = kv0 + 64;
#pragma unroll
            for (int i = 0; i < 4; ++i) {
                kreg[i] = *(const uint4*)(Kp + (size_t)(nx + krow[i]) * DH_ + kcol[i]);
                vreg[i] = *(const uint4*)(Vt + (size_t)vrow[i] * S_ + nx + vcol[i]);
            }
        }
        __syncthreads();  // Ks/Vs visible

        // S = q-scaled Q K^T  (1 m-tile x 4 n-tiles, K=128)
        // (kv0 <= q0w+15 always holds: kv0 <= t0 <= q0w)
        f32x4_t s[4] = {};
#pragma unroll
        for (int kt = 0; kt < 4; ++kt) {
            bf16x8_t kbf[4];
#pragma unroll
            for (int nt = 0; nt < 4; ++nt)
                kbf[nt] = *(const bf16x8_t*)(
                    &Ks[(nt * 16 + l16) * 128 + ((kt * 32 + quad * 8) ^ xr)]);
#pragma unroll
            for (int nt = 0; nt < 4; ++nt)
                s[nt] = __builtin_amdgcn_mfma_f32_16x16x32_bf16(
                    qf[kt], kbf[nt], s[nt], 0, 0, 0);
        }
        // causal mask (diagonal tile only)
        if (kv0 + 63 > q0w) {
#pragma unroll
            for (int nt = 0; nt < 4; ++nt)
#pragma unroll
                for (int r = 0; r < 4; ++r) {
                    int row = q0w + quad * 4 + r;
                    int col = kv0 + nt * 16 + l16;
                    if (col > row) s[nt][r] = NEG_SENTINEL;
                }
        }
        // online softmax (no clamps needed: args always <= 0; masked
        // entries give exp2(-3e38) = +0; no row is ever fully masked)
#pragma unroll
        for (int r = 0; r < 4; ++r) {
            float mx = fmaxf(fmaxf(s[0][r], s[1][r]),
                             fmaxf(s[2][r], s[3][r]));
#pragma unroll
            for (int off = 8; off >= 1; off >>= 1)
                mx = fmaxf(mx, __shfl_xor(mx, off));
            float mnew  = fmaxf(m_i[r], mx);
            float alpha = exp2f(m_i[r] - mnew);
            m_i[r] = mnew;
            float rs = 0.f;
#pragma unroll
            for (int nt = 0; nt < 4; ++nt) {
                float p = exp2f(s[nt][r] - mnew);
                s[nt][r] = p;
                rs += p;
            }
#pragma unroll
            for (int off = 8; off >= 1; off >>= 1)
                rs += __shfl_xor(rs, off);
            l_i[r] = l_i[r] * alpha + rs;
#pragma unroll
            for (int nt = 0; nt < 8; ++nt) o[nt][r] *= alpha;
        }
        // P: C/D layout -> per-wave LDS (swizzled) -> A-operand layout
#pragma unroll
        for (int nt = 0; nt < 4; ++nt)
#pragma unroll
            for (int r = 0; r < 4; ++r)
                Ps[wave][(quad * 4 + r) * 64 +
                         ((nt * 16 + l16) ^ kxor(quad * 4 + r))] = f2b(s[nt][r]);
        // O += P V
#pragma unroll
        for (int ks = 0; ks < 2; ++ks) {
            bf16x8_t pa = *(const bf16x8_t*)(
                &Ps[wave][l16 * 64 + ((ks * 32 + quad * 8) ^ xr)]);
#pragma unroll
            for (int nt = 0; nt < 8; ++nt) {
                bf16x8_t vb = *(const bf16x8_t*)(
                    &Vs[(nt * 16 + l16) * 64 + ((ks * 32 + quad * 8) ^ xr)]);
                o[nt] = __builtin_amdgcn_mfma_f32_16x16x32_bf16(
                    pa, vb, o[nt], 0, 0, 0);
            }
        }
    }
    // epilogue
#pragma unroll
    for (int r = 0; r < 4; ++r) {
        float inv = 1.f / l_i[r];
        int s_idx = q0w + quad * 4 + r;
#pragma unroll
        for (int nt = 0; nt < 8; ++nt)
            ctx[((size_t)(b * S_ + s_idx) * H_ + h) * DH_ + nt * 16 + l16] =
                f2b(o[nt][r] * inv);
    }
}

// ---------------------------------------------------------------------------
extern "C" void kernel_launch(void* const* d_in, const int* in_sizes, int n_in,
                              void* d_out, int out_size, void* d_ws, size_t ws_size,
                              hipStream_t stream) {
    const float* x  = (const float*)d_in[0];
    const float* Wq = (const float*)d_in[1];
    const float* Wk = (const float*)d_in[2];
    const float* Wv = (const float*)d_in[3];
    const float* Wo = (const float*)d_in[4];
    // d_in[5] = mask (unused; causal computed analytically)

    float* out    = (float*)d_out;                           // [B][S][H*DH]  8,388,608 f32
    float* kc_out = out + (size_t)B_ * S_ * H_ * DH_;        // [B][G][S][DH] 2,097,152 f32
    float* vc_out = kc_out + (size_t)B_ * G_ * S_ * DH_;     // [B][G][S][DH] 2,097,152 f32

    // Borrow `out` f32 region (= 16M u16) as early scratch; both buffers are
    // dead before the final gemm writes `out` (single stream, serialized).
    u16* outw = (u16*)d_out;
    u16* xb   = outw;             // 8M u16, live phases 1-2 (x cast to bf16)
    u16* qraw = outw + 8388608;   // 8M u16, live phases 2-4

    // Workspace: 16M u16 = 32 MiB, phase-safe overlays
    u16* ws    = (u16*)d_ws;
    u16* WqT   = ws;              // 4M, phases 1-2
    u16* WoT   = ws;              // 4M, phases 3-5 (transposed after q-gemm)
    u16* WkvT  = ws + 4194304;    // 2M, phases 1-2
    u16* kb    = ws + 4194304;    // 2M, phases 3-4
    u16* vt    = ws + 6291456;    // 2M, phases 3-4
    u16* kvraw = ws + 8388608;    // 4M, phases 2-3
    u16* ctx   = ws + 8388608;    // 8M, phases 4-5

    dim3 blk(256);
    // phase 1: casts + W transposes
    cast_x<<<dim3(4096), blk, 0, stream>>>(x, xb);
    transpose_f32_bf16<<<dim3(64, 64), blk, 0, stream>>>(Wq, WqT, 2048, 2048);
    transpose_f32_bf16<<<dim3(16, 64), blk, 0, stream>>>(Wk, WkvT, 2048, 512);
    transpose_f32_bf16<<<dim3(16, 64), blk, 0, stream>>>(Wv, WkvT + (size_t)512 * 2048, 2048, 512);

    // phase 2: projections
    gemm_nt<u16><<<dim3(16, 32), blk, 0, stream>>>(xb, WqT, qraw, 4096, 2048, 2048);
    gemm_nt<u16><<<dim3(8, 32),  blk, 0, stream>>>(xb, WkvT, kvraw, 4096, 1024, 2048);

    // phase 3: RoPE + cache outputs (+ Wo transpose into WqT's slot)
    transpose_f32_bf16<<<dim3(64, 64), blk, 0, stream>>>(Wo, WoT, 2048, 2048);
    rope_q<<<dim3(16384), blk, 0, stream>>>(qraw);
    k_prep<<<dim3(4096),  blk, 0, stream>>>(kvraw, kc_out, kb);
    v_prep<<<dim3(64, 4, 8), blk, 0, stream>>>(kvraw, vc_out, vt);

    // phase 4: attention (XCD-confined KV, balanced tile mapping)
    flash_attn<<<dim3(1024), blk, 0, stream>>>(qraw, kb, vt, ctx);

    // phase 5: output projection (f32 out)
    gemm_nt<float><<<dim3(16, 32), blk, 0, stream>>>(ctx, WoT, out, 4096, 2048, 2048);
}

// Round 3
// 493.097 us; speedup vs baseline: 1.4196x; 1.3847x over previous
//
#include <hip/hip_runtime.h>
#include <math.h>

typedef unsigned short u16;
typedef __bf16 bf16x8_t __attribute__((ext_vector_type(8)));
typedef float f32x4_t __attribute__((ext_vector_type(4)));
typedef float f32x16_t __attribute__((ext_vector_type(16)));

#define B_  2
#define S_  2048
#define D_  2048
#define H_  16
#define G_  4
#define DH_ 128

#define NEG_SENTINEL (-3.0e38f)
// 1/sqrt(128) * log2(e): folded into q at rope time so softmax uses exp2 directly
#define Q_SCALE (0.08838834764831843f * 1.4426950408889634f)

__device__ __forceinline__ float b2f(u16 u) {
    union { unsigned int i; float f; } v; v.i = ((unsigned int)u) << 16; return v.f;
}
__device__ __forceinline__ u16 f2b(float f) {
    union { float f; unsigned int i; } v; v.f = f;
    unsigned int r = v.i + 0x7fffu + ((v.i >> 16) & 1u);  // RNE
    return (u16)(r >> 16);
}
__device__ __forceinline__ void stc(u16* p, float v)   { *p = f2b(v); }
__device__ __forceinline__ void stc(float* p, float v) { *p = v; }

// XOR-swizzle (T2): permutes 16B chunks within a row's 8-chunk stripe.
__device__ __forceinline__ int kxor(int r) {
    return (((r) & 7) ^ (((r) >> 3) & 1)) << 3;
}

// v_cvt_pk_bf16_f32: pack two f32 -> two bf16 in one u32 (lo in low half)
__device__ __forceinline__ unsigned int cvtpk_bf16(float lo, float hi) {
    unsigned int w;
    asm("v_cvt_pk_bf16_f32 %0, %1, %2" : "=v"(w) : "v"(lo), "v"(hi));
    return w;
}

// ---------------------------------------------------------------------------
// Cast f32 -> bf16, 8 elems/thread.
// ---------------------------------------------------------------------------
__global__ __launch_bounds__(256) void cast_x(
    const float* __restrict__ in, u16* __restrict__ out) {
    int i = (blockIdx.x * 256 + threadIdx.x) * 8;
    float4 a = *(const float4*)(in + i);
    float4 b = *(const float4*)(in + i + 4);
    u16 o[8] = {f2b(a.x), f2b(a.y), f2b(a.z), f2b(a.w),
                f2b(b.x), f2b(b.y), f2b(b.z), f2b(b.w)};
    *(uint4*)(out + i) = *(uint4*)o;
}

// ---------------------------------------------------------------------------
// Transpose + cast: in f32 [R][C] -> out bf16 [C][R]. grid=(C/32, R/32)
// ---------------------------------------------------------------------------
__global__ __launch_bounds__(256) void transpose_f32_bf16(
    const float* __restrict__ in, u16* __restrict__ out, int R, int C) {
    __shared__ u16 t[32][33];
    const int c0 = blockIdx.x * 32, r0 = blockIdx.y * 32;
    const int j = threadIdx.x & 31, i = threadIdx.x >> 5;  // i in 0..7
#pragma unroll
    for (int p = 0; p < 4; ++p)
        t[i + 8 * p][j] = f2b(in[(size_t)(r0 + i + 8 * p) * C + c0 + j]);
    __syncthreads();
#pragma unroll
    for (int p = 0; p < 4; ++p)
        out[(size_t)(c0 + i + 8 * p) * R + r0 + j] = t[j][i + 8 * p];
}

// ---------------------------------------------------------------------------
// NT GEMM: C[M][N] = A[M][K] * BT[N][K]^T (bf16 in, OT out, f32 acc)
// block = 256 (4 waves), tile 128x128, BK=64. grid=(N/128, M/128)
// ---------------------------------------------------------------------------
template <typename OT>
__global__ __launch_bounds__(256) void gemm_nt(
    const u16* __restrict__ A, const u16* __restrict__ BT, OT* __restrict__ C,
    int M, int N, int K) {
    __shared__ __align__(16) u16 As[128 * 72];
    __shared__ __align__(16) u16 Bs[128 * 72];
    const int tid  = threadIdx.x;
    const int lane = tid & 63;
    const int wave = tid >> 6;
    const int wm = wave >> 1, wn = wave & 1;
    const int quad = lane >> 4, l16 = lane & 15;
    const int m0 = blockIdx.y * 128, n0 = blockIdx.x * 128;

    f32x4_t acc[4][4] = {};

    for (int k0 = 0; k0 < K; k0 += 64) {
#pragma unroll
        for (int c = tid; c < 1024; c += 256) {
            int row = c >> 3, cc = (c & 7) << 3;
            *(uint4*)(&As[row * 72 + cc]) =
                *(const uint4*)(A + (size_t)(m0 + row) * K + k0 + cc);
            *(uint4*)(&Bs[row * 72 + cc]) =
                *(const uint4*)(BT + (size_t)(n0 + row) * K + k0 + cc);
        }
        __syncthreads();
#pragma unroll
        for (int ks = 0; ks < 2; ++ks) {
            const int koff = ks * 32 + quad * 8;
            bf16x8_t a[4], b[4];
#pragma unroll
            for (int mt = 0; mt < 4; ++mt)
                a[mt] = *(const bf16x8_t*)(&As[(wm * 64 + mt * 16 + l16) * 72 + koff]);
#pragma unroll
            for (int nt = 0; nt < 4; ++nt)
                b[nt] = *(const bf16x8_t*)(&Bs[(wn * 64 + nt * 16 + l16) * 72 + koff]);
#pragma unroll
            for (int mt = 0; mt < 4; ++mt)
#pragma unroll
                for (int nt = 0; nt < 4; ++nt)
                    acc[mt][nt] = __builtin_amdgcn_mfma_f32_16x16x32_bf16(
                        a[mt], b[nt], acc[mt][nt], 0, 0, 0);
        }
        __syncthreads();
    }
#pragma unroll
    for (int mt = 0; mt < 4; ++mt)
#pragma unroll
        for (int nt = 0; nt < 4; ++nt)
#pragma unroll
            for (int r = 0; r < 4; ++r) {
                int m = m0 + wm * 64 + mt * 16 + quad * 4 + r;
                int n = n0 + wn * 64 + nt * 16 + l16;
                stc(C + (size_t)m * N + n, acc[mt][nt][r]);
            }
}

// ---------------------------------------------------------------------------
// RoPE on q in-place (bf16), folding Q_SCALE (softmax scale * log2e) into q.
// q layout [B][S][H][DH].
// ---------------------------------------------------------------------------
__global__ __launch_bounds__(256) void rope_q(u16* q) {
    int idx = blockIdx.x * 256 + threadIdx.x;
    int d = idx & 63;
    int t = idx >> 6;
    int h = t & 15; t >>= 4;
    int s = t & 2047;
    int b = t >> 11;
    size_t base = ((size_t)(b * S_ + s) * H_ + h) * DH_;
    float x1 = b2f(q[base + d]), x2 = b2f(q[base + d + 64]);
    float inv = exp2f(-(float)d * (13.287712379549449f / 64.f));  // 10000^(-d/64)
    float ang = (float)s * inv, sn, cs;
    sincosf(ang, &sn, &cs);
    q[base + d]      = f2b((x1 * cs - x2 * sn) * Q_SCALE);
    q[base + d + 64] = f2b((x2 * cs + x1 * sn) * Q_SCALE);
}

// ---------------------------------------------------------------------------
// RoPE on k: kvraw bf16 [B*S][1024] (cols 0..511 = k) ->
//   kc f32 [B][G][S][DH] (output) and kb bf16 same layout (for MFMA)
// ---------------------------------------------------------------------------
__global__ __launch_bounds__(256) void k_prep(
    const u16* __restrict__ kvraw, float* __restrict__ kc, u16* __restrict__ kb) {
    int idx = blockIdx.x * 256 + threadIdx.x;
    int d = idx & 63;
    int t = idx >> 6;
    int g = t & 3; t >>= 2;
    int s = t & 2047;
    int b = t >> 11;
    const u16* src = kvraw + (size_t)(b * S_ + s) * 1024 + g * DH_;
    float x1 = b2f(src[d]), x2 = b2f(src[d + 64]);
    float inv = exp2f(-(float)d * (13.287712379549449f / 64.f));
    float ang = (float)s * inv, sn, cs;
    sincosf(ang, &sn, &cs);
    float r1 = x1 * cs - x2 * sn;
    float r2 = x2 * cs + x1 * sn;
    size_t o = ((size_t)(b * G_ + g) * S_ + s) * DH_;
    kc[o + d]      = r1;
    kc[o + d + 64] = r2;
    kb[o + d]      = f2b(r1);
    kb[o + d + 64] = f2b(r2);
}

// ---------------------------------------------------------------------------
// v: emit v_cache f32 [B][G][S][DH] and v^T bf16 [B][G][DH][S]
// grid=(S/32, DH/32, B*G), block=256
// ---------------------------------------------------------------------------
__global__ __launch_bounds__(256) void v_prep(
    const u16* __restrict__ kvraw, float* __restrict__ vc, u16* __restrict__ vt) {
    __shared__ u16 t[32][33];
    const int s0 = blockIdx.x * 32, d0 = blockIdx.y * 32;
    const int bg = blockIdx.z, b = bg >> 2, g = bg & 3;
    const int j = threadIdx.x & 31, i = threadIdx.x >> 5;
#pragma unroll
    for (int p = 0; p < 4; ++p) {
        int s = s0 + i + 8 * p;
        u16 v = kvraw[(size_t)(b * S_ + s) * 1024 + 512 + g * DH_ + d0 + j];
        t[i + 8 * p][j] = v;
        vc[((size_t)bg * S_ + s) * DH_ + d0 + j] = b2f(v);
    }
    __syncthreads();
#pragma unroll
    for (int p = 0; p < 4; ++p)
        vt[((size_t)bg * DH_ + d0 + i + 8 * p) * S_ + s0 + j] = t[j][i + 8 * p];
}

// ---------------------------------------------------------------------------
// Flash attention v6: 32x32 MFMA, swapped QK^T, in-register softmax.
// grid=(8, H, B), block=256 (4 waves x 32 q-rows = 128-row tile), 1 block/CU.
// Block x processes paired tiles {x, 15-x} (34 kv-iters total, uniform).
//
// Swapped QK^T: s = mfma_32x32x16(A=K[kv][d], B=Q[q][d]) accumulated over
// d=128. D layout: col=lane&31 = q (lane owns ONE q-row), row = crow(r,hi) =
// (r&3)+8*(r>>2)+4*hi = kv. Row max/sum = in-register tree + ONE
// __shfl_xor(,32) -- replaces the old 4x(two 4-deep butterflies) chains.
// P -> PV A-operand via v_cvt_pk_bf16_f32 + v_permlane32_swap_b32 (T12):
// pa[ks] = [a0',a1',b0',b1'] where swap(a0=pk(p[8u],p[8u+1]),
// b0=pk(p[8u+4],p[8u+5])) etc (u=ks&1, t=ks>>1) gives lane-half hi=0 the
// k=16u+0..7 slice and hi=1 the k=16u+8..15 slice of tile t -- no LDS Ps.
// Defer-max (T13, THR=8): skip O-rescale while pmax <= m+8 (P bounded 2^8).
// K/V double-buffered in LDS (64 KiB, XOR-swizzled): ONE barrier per iter.
// ---------------------------------------------------------------------------
__global__ __launch_bounds__(256, 1) void flash_attn(
    const u16* __restrict__ q, const u16* __restrict__ kb,
    const u16* __restrict__ vt, u16* __restrict__ ctx) {
    __shared__ __align__(16) u16 Ks[2][64 * 128];   // [buf][kv 64][d 128], swz
    __shared__ __align__(16) u16 Vs[2][128 * 64];   // [buf][d 128][kv 64], swz

    const int tid  = threadIdx.x;
    const int lane = tid & 63;
    const int wave = tid >> 6;
    const int hi = lane >> 5, l31 = lane & 31;
    const int h = blockIdx.y, b = blockIdx.z;
    const int g = h >> 2;  // H/G = 4
    const u16* Kp  = kb + (size_t)(b * G_ + g) * S_ * DH_;
    const u16* Vtp = vt + (size_t)(b * G_ + g) * DH_ * S_;

    // staging chunk coords (4 chunks of 16B per thread for each of K,V)
    int krow[4], kcol[4], vrow[4], vcol[4];
#pragma unroll
    for (int i = 0; i < 4; ++i) {
        int c = tid + 256 * i;
        krow[i] = c >> 4; kcol[i] = (c & 15) << 3;
        vrow[i] = c >> 3; vcol[i] = (c & 7) << 3;
    }

#pragma unroll
    for (int half = 0; half < 2; ++half) {
        const int tile = half ? (15 - (int)blockIdx.x) : (int)blockIdx.x;
        const int t0 = tile * 128;
        const int q0w = t0 + wave * 32;
        const int niter = 2 * tile + 2;

        // Q fragments (B-operand): lane: n = l31 -> q row, k = dk*16+hi*8+j
        bf16x8_t qf[8];
#pragma unroll
        for (int dk = 0; dk < 8; ++dk)
            qf[dk] = *(const bf16x8_t*)(
                q + ((size_t)(b * S_ + q0w + l31) * H_ + h) * DH_ + dk * 16 + hi * 8);

        f32x16_t o[4] = {};   // O[q=crow(r,hi)][d = nb*32 + l31]
        float m_i = NEG_SENTINEL, l_i = 0.f;

        // stage tile 0 into buf0; preload tile 1 into regs
        uint4 kreg[4], vreg[4];
#pragma unroll
        for (int i = 0; i < 4; ++i) {
            kreg[i] = *(const uint4*)(Kp + (size_t)krow[i] * DH_ + kcol[i]);
            vreg[i] = *(const uint4*)(Vtp + (size_t)vrow[i] * S_ + vcol[i]);
        }
#pragma unroll
        for (int i = 0; i < 4; ++i) {
            *(uint4*)(&Ks[0][krow[i] * 128 + (kcol[i] ^ kxor(krow[i]))]) = kreg[i];
            *(uint4*)(&Vs[0][vrow[i] * 64 + (vcol[i] ^ kxor(vrow[i]))]) = vreg[i];
        }
        if (niter > 1) {
#pragma unroll
            for (int i = 0; i < 4; ++i) {
                kreg[i] = *(const uint4*)(Kp + (size_t)(64 + krow[i]) * DH_ + kcol[i]);
                vreg[i] = *(const uint4*)(Vtp + (size_t)vrow[i] * S_ + 64 + vcol[i]);
            }
        }

        for (int it = 0; it < niter; ++it) {
            const int kv0 = it * 64;
            __syncthreads();  // buf[it&1] writes (from prev iter) visible
            if (it + 1 < niter) {
                const int bw = (it + 1) & 1;
#pragma unroll
                for (int i = 0; i < 4; ++i) {
                    *(uint4*)(&Ks[bw][krow[i] * 128 + (kcol[i] ^ kxor(krow[i]))]) = kreg[i];
                    *(uint4*)(&Vs[bw][vrow[i] * 64 + (vcol[i] ^ kxor(vrow[i]))]) = vreg[i];
                }
                if (it + 2 < niter) {
                    const int nx = kv0 + 128;
#pragma unroll
                    for (int i = 0; i < 4; ++i) {
                        kreg[i] = *(const uint4*)(Kp + (size_t)(nx + krow[i]) * DH_ + kcol[i]);
                        vreg[i] = *(const uint4*)(Vtp + (size_t)vrow[i] * S_ + nx + vcol[i]);
                    }
                }
            }

            if (q0w + 31 >= kv0) {  // wave-uniform: skip fully-masked iters
                const u16* Kb = Ks[it & 1];
                const u16* Vb = Vs[it & 1];

                // S = K Q^T : s[t][r] = P[kv = kv0+t*32+crow(r,hi)][q = q0w+l31]
                f32x16_t s[2] = {};
#pragma unroll
                for (int dk = 0; dk < 8; ++dk) {
                    const int col = dk * 16 + hi * 8;
                    bf16x8_t kf0 = *(const bf16x8_t*)(
                        &Kb[l31 * 128 + (col ^ kxor(l31))]);
                    bf16x8_t kf1 = *(const bf16x8_t*)(
                        &Kb[(32 + l31) * 128 + (col ^ kxor(32 + l31))]);
                    s[0] = __builtin_amdgcn_mfma_f32_32x32x16_bf16(kf0, qf[dk], s[0], 0, 0, 0);
                    s[1] = __builtin_amdgcn_mfma_f32_32x32x16_bf16(kf1, qf[dk], s[1], 0, 0, 0);
                }
                // causal mask (diagonal region only)
                if (kv0 + 63 > q0w) {
                    const int qg = q0w + l31;
#pragma unroll
                    for (int t = 0; t < 2; ++t)
#pragma unroll
                        for (int r = 0; r < 16; ++r) {
                            int kvr = kv0 + t * 32 + (r & 3) + 8 * (r >> 2) + 4 * hi;
                            if (kvr > qg) s[t][r] = NEG_SENTINEL;
                        }
                }
                // row max: in-register tree + one cross-half exchange
                float red[16];
#pragma unroll
                for (int i = 0; i < 16; ++i) red[i] = fmaxf(s[0][i], s[1][i]);
#pragma unroll
                for (int w = 8; w >= 1; w >>= 1)
#pragma unroll
                    for (int i = 0; i < w; ++i) red[i] = fmaxf(red[i], red[i + w]);
                float pmax = fmaxf(red[0], __shfl_xor(red[0], 32));
                // defer-max (T13): rescale only when max grew past threshold
                if (!__all(pmax - m_i <= 8.f)) {
                    float mnew  = fmaxf(m_i, pmax);
                    float alpha = exp2f(m_i - mnew);
                    m_i = mnew;
                    l_i *= alpha;
#pragma unroll
                    for (int nb = 0; nb < 4; ++nb)
#pragma unroll
                        for (int r = 0; r < 16; ++r) o[nb][r] *= alpha;
                }
                // P = exp2(s - m), row sum (tree + one exchange)
                float sum[16];
#pragma unroll
                for (int i = 0; i < 16; ++i) {
                    float p0 = exp2f(s[0][i] - m_i);
                    float p1 = exp2f(s[1][i] - m_i);
                    s[0][i] = p0; s[1][i] = p1;
                    sum[i] = p0 + p1;
                }
#pragma unroll
                for (int w = 8; w >= 1; w >>= 1)
#pragma unroll
                    for (int i = 0; i < w; ++i) sum[i] += sum[i + w];
                l_i += sum[0] + __shfl_xor(sum[0], 32);

                // P -> bf16 A-operand fragments (cvt_pk + permlane32_swap)
                bf16x8_t pa[4];
#pragma unroll
                for (int ks = 0; ks < 4; ++ks) {
                    const int t = ks >> 1, u8 = (ks & 1) * 8;
                    unsigned int a0 = cvtpk_bf16(s[t][u8 + 0], s[t][u8 + 1]);
                    unsigned int a1 = cvtpk_bf16(s[t][u8 + 2], s[t][u8 + 3]);
                    unsigned int b0 = cvtpk_bf16(s[t][u8 + 4], s[t][u8 + 5]);
                    unsigned int b1 = cvtpk_bf16(s[t][u8 + 6], s[t][u8 + 7]);
                    asm("v_permlane32_swap_b32 %0, %1" : "+v"(a0), "+v"(b0));
                    asm("v_permlane32_swap_b32 %0, %1" : "+v"(a1), "+v"(b1));
                    union { unsigned int w[4]; bf16x8_t v; } pk;
                    pk.w[0] = a0; pk.w[1] = a1; pk.w[2] = b0; pk.w[3] = b1;
                    pa[ks] = pk.v;
                }
                // O += P V : B-operand from Vs[d][kv]
#pragma unroll
                for (int ks = 0; ks < 4; ++ks) {
                    const int col = ks * 16 + hi * 8;
#pragma unroll
                    for (int nb = 0; nb < 4; ++nb) {
                        const int row = nb * 32 + l31;
                        bf16x8_t vb = *(const bf16x8_t*)(
                            &Vb[row * 64 + (col ^ kxor(row))]);
                        o[nb] = __builtin_amdgcn_mfma_f32_32x32x16_bf16(
                            pa[ks], vb, o[nb], 0, 0, 0);
                    }
                }
            }
        }
        // epilogue: normalize rows; 1/l lives in lane (q = l31); rows need
        // lane crow(r,hi)'s value -> wave broadcast shfl
        float il = 1.f / l_i;
#pragma unroll
        for (int r = 0; r < 16; ++r) {
            const int crow = (r & 3) + 8 * (r >> 2) + 4 * hi;
            float ilr = __shfl(il, crow);
            const int s_idx = q0w + crow;
#pragma unroll
            for (int nb = 0; nb < 4; ++nb)
                ctx[((size_t)(b * S_ + s_idx) * H_ + h) * DH_ + nb * 32 + l31] =
                    f2b(o[nb][r] * ilr);
        }
        __syncthreads();  // all waves done with Ks/Vs before next half restages
    }
}

// ---------------------------------------------------------------------------
extern "C" void kernel_launch(void* const* d_in, const int* in_sizes, int n_in,
                              void* d_out, int out_size, void* d_ws, size_t ws_size,
                              hipStream_t stream) {
    const float* x  = (const float*)d_in[0];
    const float* Wq = (const float*)d_in[1];
    const float* Wk = (const float*)d_in[2];
    const float* Wv = (const float*)d_in[3];
    const float* Wo = (const float*)d_in[4];
    // d_in[5] = mask (unused; causal computed analytically)

    float* out    = (float*)d_out;                           // [B][S][H*DH]  8,388,608 f32
    float* kc_out = out + (size_t)B_ * S_ * H_ * DH_;        // [B][G][S][DH] 2,097,152 f32
    float* vc_out = kc_out + (size_t)B_ * G_ * S_ * DH_;     // [B][G][S][DH] 2,097,152 f32

    // Borrow `out` f32 region (= 16M u16) as early scratch; both buffers are
    // dead before the final gemm writes `out` (single stream, serialized).
    u16* outw = (u16*)d_out;
    u16* xb   = outw;             // 8M u16, live phases 1-2 (x cast to bf16)
    u16* qraw = outw + 8388608;   // 8M u16, live phases 2-4

    // Workspace: 16M u16 = 32 MiB, phase-safe overlays
    u16* ws    = (u16*)d_ws;
    u16* WqT   = ws;              // 4M, phases 1-2
    u16* WoT   = ws;              // 4M, phases 3-5 (transposed after q-gemm)
    u16* WkvT  = ws + 4194304;    // 2M, phases 1-2
    u16* kb    = ws + 4194304;    // 2M, phases 3-4
    u16* vt    = ws + 6291456;    // 2M, phases 3-4
    u16* kvraw = ws + 8388608;    // 4M, phases 2-3
    u16* ctx   = ws + 8388608;    // 8M, phases 4-5

    dim3 blk(256);
    // phase 1: casts + W transposes
    cast_x<<<dim3(4096), blk, 0, stream>>>(x, xb);
    transpose_f32_bf16<<<dim3(64, 64), blk, 0, stream>>>(Wq, WqT, 2048, 2048);
    transpose_f32_bf16<<<dim3(16, 64), blk, 0, stream>>>(Wk, WkvT, 2048, 512);
    transpose_f32_bf16<<<dim3(16, 64), blk, 0, stream>>>(Wv, WkvT + (size_t)512 * 2048, 2048, 512);

    // phase 2: projections
    gemm_nt<u16><<<dim3(16, 32), blk, 0, stream>>>(xb, WqT, qraw, 4096, 2048, 2048);
    gemm_nt<u16><<<dim3(8, 32),  blk, 0, stream>>>(xb, WkvT, kvraw, 4096, 1024, 2048);

    // phase 3: RoPE + cache outputs (+ Wo transpose into WqT's slot)
    transpose_f32_bf16<<<dim3(64, 64), blk, 0, stream>>>(Wo, WoT, 2048, 2048);
    rope_q<<<dim3(16384), blk, 0, stream>>>(qraw);
    k_prep<<<dim3(4096),  blk, 0, stream>>>(kvraw, kc_out, kb);
    v_prep<<<dim3(64, 4, 8), blk, 0, stream>>>(kvraw, vc_out, vt);

    // phase 4: attention (32x32 swapped-QK^T, paired tiles, 1 block/CU)
    flash_attn<<<dim3(8, 16, 2), blk, 0, stream>>>(qraw, kb, vt, ctx);

    // phase 5: output projection (f32 out)
    gemm_nt<float><<<dim3(16, 32), blk, 0, stream>>>(ctx, WoT, out, 4096, 2048, 2048);
}

// Round 4
// 438.205 us; speedup vs baseline: 1.5975x; 1.1253x over previous
//
#include <hip/hip_runtime.h>
#include <math.h>

typedef unsigned short u16;
typedef __bf16 bf16x8_t __attribute__((ext_vector_type(8)));
typedef float f32x4_t __attribute__((ext_vector_type(4)));
typedef float f32x16_t __attribute__((ext_vector_type(16)));

#define B_  2
#define S_  2048
#define D_  2048
#define H_  16
#define G_  4
#define DH_ 128

#define NEG_SENTINEL (-3.0e38f)
// 1/sqrt(128) * log2(e): folded into q at rope time so softmax uses exp2 directly
#define Q_SCALE (0.08838834764831843f * 1.4426950408889634f)

__device__ __forceinline__ float b2f(u16 u) {
    union { unsigned int i; float f; } v; v.i = ((unsigned int)u) << 16; return v.f;
}
__device__ __forceinline__ u16 f2b(float f) {
    union { float f; unsigned int i; } v; v.f = f;
    unsigned int r = v.i + 0x7fffu + ((v.i >> 16) & 1u);  // RNE
    return (u16)(r >> 16);
}
__device__ __forceinline__ void stc(u16* p, float v)   { *p = f2b(v); }
__device__ __forceinline__ void stc(float* p, float v) { *p = v; }

// XOR-swizzle (T2): permutes 16B chunks within a row's 8-chunk stripe.
__device__ __forceinline__ int kxor(int r) {
    return (((r) & 7) ^ (((r) >> 3) & 1)) << 3;
}
// chunk-index involution for gemm LDS (8 chunks of 16B per 64-elem row)
__device__ __forceinline__ int swz8(int r) { return (r & 7) ^ ((r >> 3) & 1); }

// async global->LDS, 16B per lane (dest = wave-uniform base + lane*16)
__device__ __forceinline__ void gld16(const u16* g, u16* l) {
    __builtin_amdgcn_global_load_lds(
        (const __attribute__((address_space(1))) unsigned int*)g,
        (__attribute__((address_space(3))) unsigned int*)l, 16, 0, 0);
}

// v_cvt_pk_bf16_f32: pack two f32 -> two bf16 in one u32 (lo in low half)
__device__ __forceinline__ unsigned int cvtpk_bf16(float lo, float hi) {
    unsigned int w;
    asm("v_cvt_pk_bf16_f32 %0, %1, %2" : "=v"(w) : "v"(lo), "v"(hi));
    return w;
}

// ---------------------------------------------------------------------------
// Cast f32 -> bf16, 8 elems/thread.
// ---------------------------------------------------------------------------
__global__ __launch_bounds__(256) void cast_x(
    const float* __restrict__ in, u16* __restrict__ out) {
    int i = (blockIdx.x * 256 + threadIdx.x) * 8;
    float4 a = *(const float4*)(in + i);
    float4 b = *(const float4*)(in + i + 4);
    u16 o[8] = {f2b(a.x), f2b(a.y), f2b(a.z), f2b(a.w),
                f2b(b.x), f2b(b.y), f2b(b.z), f2b(b.w)};
    *(uint4*)(out + i) = *(uint4*)o;
}

// ---------------------------------------------------------------------------
// Transpose + cast: in f32 [R][C] -> out bf16 [C][R]. grid=(C/32, R/32)
// ---------------------------------------------------------------------------
__global__ __launch_bounds__(256) void transpose_f32_bf16(
    const float* __restrict__ in, u16* __restrict__ out, int R, int C) {
    __shared__ u16 t[32][33];
    const int c0 = blockIdx.x * 32, r0 = blockIdx.y * 32;
    const int j = threadIdx.x & 31, i = threadIdx.x >> 5;  // i in 0..7
#pragma unroll
    for (int p = 0; p < 4; ++p)
        t[i + 8 * p][j] = f2b(in[(size_t)(r0 + i + 8 * p) * C + c0 + j]);
    __syncthreads();
#pragma unroll
    for (int p = 0; p < 4; ++p)
        out[(size_t)(c0 + i + 8 * p) * R + r0 + j] = t[j][i + 8 * p];
}

// ---------------------------------------------------------------------------
// NT GEMM: C[M][N] = A[M][K] * BT[N][K]^T (bf16 in, OT out, f32 acc)
// block = 256 (4 waves), tile 128x128, BK=64. grid=(N/128, M/128)
// Staging via global_load_lds width=16 (m97 recipe): LDS linear [128][64],
// chunk swizzle swz8 applied to the per-lane GLOBAL source address and to
// the LDS read (rule 21: linear dest + inverse-swz source + swz read).
// ---------------------------------------------------------------------------
template <typename OT>
__global__ __launch_bounds__(256) void gemm_nt(
    const u16* __restrict__ A, const u16* __restrict__ BT, OT* __restrict__ C,
    int M, int N, int K) {
    __shared__ __align__(16) u16 As[128 * 64];
    __shared__ __align__(16) u16 Bs[128 * 64];
    const int tid  = threadIdx.x;
    const int lane = tid & 63;
    const int wave = tid >> 6;
    const int wm = wave >> 1, wn = wave & 1;
    const int quad = lane >> 4, l16 = lane & 15;
    const int lr = lane >> 3, lc = lane & 7;   // staging: row-in-8, chunk
    const int m0 = blockIdx.y * 128, n0 = blockIdx.x * 128;

    f32x4_t acc[4][4] = {};

    for (int k0 = 0; k0 < K; k0 += 64) {
#pragma unroll
        for (int i = 0; i < 4; ++i) {
            int rb = wave * 32 + i * 8;       // 8-row stripe this wave writes
            int r  = rb + lr;                 // row this lane fetches
            int sc = (lc ^ swz8(r)) << 3;     // swizzled source column
            gld16(A  + (size_t)(m0 + r) * K + k0 + sc, &As[rb * 64]);
            gld16(BT + (size_t)(n0 + r) * K + k0 + sc, &Bs[rb * 64]);
        }
        __syncthreads();   // drains vmcnt (compiler-inserted) + barrier
#pragma unroll
        for (int ks = 0; ks < 2; ++ks) {
            const int kch = ks * 4 + quad;    // chunk index of this frag
            bf16x8_t a[4], b[4];
#pragma unroll
            for (int mt = 0; mt < 4; ++mt) {
                int row = wm * 64 + mt * 16 + l16;
                a[mt] = *(const bf16x8_t*)(&As[row * 64 + ((kch ^ swz8(row)) << 3)]);
            }
#pragma unroll
            for (int nt = 0; nt < 4; ++nt) {
                int row = wn * 64 + nt * 16 + l16;
                b[nt] = *(const bf16x8_t*)(&Bs[row * 64 + ((kch ^ swz8(row)) << 3)]);
            }
#pragma unroll
            for (int mt = 0; mt < 4; ++mt)
#pragma unroll
                for (int nt = 0; nt < 4; ++nt)
                    acc[mt][nt] = __builtin_amdgcn_mfma_f32_16x16x32_bf16(
                        a[mt], b[nt], acc[mt][nt], 0, 0, 0);
        }
        __syncthreads();
    }
#pragma unroll
    for (int mt = 0; mt < 4; ++mt)
#pragma unroll
        for (int nt = 0; nt < 4; ++nt)
#pragma unroll
            for (int r = 0; r < 4; ++r) {
                int m = m0 + wm * 64 + mt * 16 + quad * 4 + r;
                int n = n0 + wn * 64 + nt * 16 + l16;
                stc(C + (size_t)m * N + n, acc[mt][nt][r]);
            }
}

// ---------------------------------------------------------------------------
// RoPE on q in-place (bf16), folding Q_SCALE (softmax scale * log2e) into q.
// q layout [B][S][H][DH].
// ---------------------------------------------------------------------------
__global__ __launch_bounds__(256) void rope_q(u16* q) {
    int idx = blockIdx.x * 256 + threadIdx.x;
    int d = idx & 63;
    int t = idx >> 6;
    int h = t & 15; t >>= 4;
    int s = t & 2047;
    int b = t >> 11;
    size_t base = ((size_t)(b * S_ + s) * H_ + h) * DH_;
    float x1 = b2f(q[base + d]), x2 = b2f(q[base + d + 64]);
    float inv = exp2f(-(float)d * (13.287712379549449f / 64.f));  // 10000^(-d/64)
    float ang = (float)s * inv, sn, cs;
    sincosf(ang, &sn, &cs);
    q[base + d]      = f2b((x1 * cs - x2 * sn) * Q_SCALE);
    q[base + d + 64] = f2b((x2 * cs + x1 * sn) * Q_SCALE);
}

// ---------------------------------------------------------------------------
// RoPE on k: kvraw bf16 [B*S][1024] (cols 0..511 = k) ->
//   kc f32 [B][G][S][DH] (output) and kb bf16 same layout (for MFMA)
// ---------------------------------------------------------------------------
__global__ __launch_bounds__(256) void k_prep(
    const u16* __restrict__ kvraw, float* __restrict__ kc, u16* __restrict__ kb) {
    int idx = blockIdx.x * 256 + threadIdx.x;
    int d = idx & 63;
    int t = idx >> 6;
    int g = t & 3; t >>= 2;
    int s = t & 2047;
    int b = t >> 11;
    const u16* src = kvraw + (size_t)(b * S_ + s) * 1024 + g * DH_;
    float x1 = b2f(src[d]), x2 = b2f(src[d + 64]);
    float inv = exp2f(-(float)d * (13.287712379549449f / 64.f));
    float ang = (float)s * inv, sn, cs;
    sincosf(ang, &sn, &cs);
    float r1 = x1 * cs - x2 * sn;
    float r2 = x2 * cs + x1 * sn;
    size_t o = ((size_t)(b * G_ + g) * S_ + s) * DH_;
    kc[o + d]      = r1;
    kc[o + d + 64] = r2;
    kb[o + d]      = f2b(r1);
    kb[o + d + 64] = f2b(r2);
}

// ---------------------------------------------------------------------------
// v: emit v_cache f32 [B][G][S][DH] and v^T bf16 [B][G][DH][S]
// grid=(S/32, DH/32, B*G), block=256
// ---------------------------------------------------------------------------
__global__ __launch_bounds__(256) void v_prep(
    const u16* __restrict__ kvraw, float* __restrict__ vc, u16* __restrict__ vt) {
    __shared__ u16 t[32][33];
    const int s0 = blockIdx.x * 32, d0 = blockIdx.y * 32;
    const int bg = blockIdx.z, b = bg >> 2, g = bg & 3;
    const int j = threadIdx.x & 31, i = threadIdx.x >> 5;
#pragma unroll
    for (int p = 0; p < 4; ++p) {
        int s = s0 + i + 8 * p;
        u16 v = kvraw[(size_t)(b * S_ + s) * 1024 + 512 + g * DH_ + d0 + j];
        t[i + 8 * p][j] = v;
        vc[((size_t)bg * S_ + s) * DH_ + d0 + j] = b2f(v);
    }
    __syncthreads();
#pragma unroll
    for (int p = 0; p < 4; ++p)
        vt[((size_t)bg * DH_ + d0 + i + 8 * p) * S_ + s0 + j] = t[j][i + 8 * p];
}

// ---------------------------------------------------------------------------
// Flash attention v7: 32x32 swapped QK^T, in-register softmax, 2 blocks/CU.
// grid=(512) 1-D, block=256 (4 waves x 32 q-rows = 128-row tile).
// Decode: tslot=id&7, h=(id>>3)&15, b=id>>7 (within low 256);
//   tile = (id>>8) ? 15-tslot : tslot.
// Under XCD round-robin (XCD=id%8), blocks i and i+256 co-reside on one CU
// with complementary tiles {t, 15-t} = 34 kv-iters/CU (balanced), and the
// WHOLE grid is co-resident (512 blocks = 2/CU, LDS 2x81920 = 160 KiB
// exactly) -> all blocks sweep kv from 0 in lockstep -> L2-shared K/V reads
// (no drift: nothing retires and gets replaced).
// ---------------------------------------------------------------------------
__global__ __launch_bounds__(256, 1) void flash_attn(
    const u16* __restrict__ q, const u16* __restrict__ kb,
    const u16* __restrict__ vt, u16* __restrict__ ctx) {
    __shared__ __align__(16) u16 Ks[2][64 * 128];   // [buf][kv 64][d 128], swz
    __shared__ __align__(16) u16 Vs[2][128 * 64];   // [buf][d 128][kv 64], swz

    const int tid  = threadIdx.x;
    const int lane = tid & 63;
    const int wave = tid >> 6;
    const int hi = lane >> 5, l31 = lane & 31;

    const int id = blockIdx.x;
    const int tslot = id & 7;
    const int h = (id >> 3) & 15;
    const int b = (id >> 7) & 1;
    const int tile = (id >> 8) ? (15 - tslot) : tslot;
    const int g = h >> 2;  // H/G = 4

    const u16* Kp  = kb + (size_t)(b * G_ + g) * S_ * DH_;
    const u16* Vtp = vt + (size_t)(b * G_ + g) * DH_ * S_;

    // staging chunk coords (4 chunks of 16B per thread for each of K,V)
    int krow[4], kcol[4], vrow[4], vcol[4];
#pragma unroll
    for (int i = 0; i < 4; ++i) {
        int c = tid + 256 * i;
        krow[i] = c >> 4; kcol[i] = (c & 15) << 3;
        vrow[i] = c >> 3; vcol[i] = (c & 7) << 3;
    }

    const int t0 = tile * 128;
    const int q0w = t0 + wave * 32;
    const int niter = 2 * tile + 2;

    // Q fragments (B-operand): lane: n = l31 -> q row, k = dk*16+hi*8+j
    bf16x8_t qf[8];
#pragma unroll
    for (int dk = 0; dk < 8; ++dk)
        qf[dk] = *(const bf16x8_t*)(
            q + ((size_t)(b * S_ + q0w + l31) * H_ + h) * DH_ + dk * 16 + hi * 8);

    f32x16_t o[4] = {};   // O[q=crow(r,hi)][d = nb*32 + l31]
    float m_i = NEG_SENTINEL, l_i = 0.f;

    // stage tile 0 into buf0; preload tile 1 into regs
    uint4 kreg[4], vreg[4];
#pragma unroll
    for (int i = 0; i < 4; ++i) {
        kreg[i] = *(const uint4*)(Kp + (size_t)krow[i] * DH_ + kcol[i]);
        vreg[i] = *(const uint4*)(Vtp + (size_t)vrow[i] * S_ + vcol[i]);
    }
#pragma unroll
    for (int i = 0; i < 4; ++i) {
        *(uint4*)(&Ks[0][krow[i] * 128 + (kcol[i] ^ kxor(krow[i]))]) = kreg[i];
        *(uint4*)(&Vs[0][vrow[i] * 64 + (vcol[i] ^ kxor(vrow[i]))]) = vreg[i];
    }
    if (niter > 1) {
#pragma unroll
        for (int i = 0; i < 4; ++i) {
            kreg[i] = *(const uint4*)(Kp + (size_t)(64 + krow[i]) * DH_ + kcol[i]);
            vreg[i] = *(const uint4*)(Vtp + (size_t)vrow[i] * S_ + 64 + vcol[i]);
        }
    }

    for (int it = 0; it < niter; ++it) {
        const int kv0 = it * 64;
        __syncthreads();  // buf[it&1] writes (from prev iter) visible
        if (it + 1 < niter) {
            const int bw = (it + 1) & 1;
#pragma unroll
            for (int i = 0; i < 4; ++i) {
                *(uint4*)(&Ks[bw][krow[i] * 128 + (kcol[i] ^ kxor(krow[i]))]) = kreg[i];
                *(uint4*)(&Vs[bw][vrow[i] * 64 + (vcol[i] ^ kxor(vrow[i]))]) = vreg[i];
            }
            if (it + 2 < niter) {
                const int nx = kv0 + 128;
#pragma unroll
                for (int i = 0; i < 4; ++i) {
                    kreg[i] = *(const uint4*)(Kp + (size_t)(nx + krow[i]) * DH_ + kcol[i]);
                    vreg[i] = *(const uint4*)(Vtp + (size_t)vrow[i] * S_ + nx + vcol[i]);
                }
            }
        }

        if (q0w + 31 >= kv0) {  // wave-uniform: skip fully-masked iters
            const u16* Kb = Ks[it & 1];
            const u16* Vb = Vs[it & 1];

            // S = K Q^T : s[t][r] = P[kv = kv0+t*32+crow(r,hi)][q = q0w+l31]
            f32x16_t s[2] = {};
#pragma unroll
            for (int dk = 0; dk < 8; ++dk) {
                const int col = dk * 16 + hi * 8;
                bf16x8_t kf0 = *(const bf16x8_t*)(
                    &Kb[l31 * 128 + (col ^ kxor(l31))]);
                bf16x8_t kf1 = *(const bf16x8_t*)(
                    &Kb[(32 + l31) * 128 + (col ^ kxor(32 + l31))]);
                s[0] = __builtin_amdgcn_mfma_f32_32x32x16_bf16(kf0, qf[dk], s[0], 0, 0, 0);
                s[1] = __builtin_amdgcn_mfma_f32_32x32x16_bf16(kf1, qf[dk], s[1], 0, 0, 0);
            }
            // causal mask (diagonal region only)
            if (kv0 + 63 > q0w) {
                const int qg = q0w + l31;
#pragma unroll
                for (int t = 0; t < 2; ++t)
#pragma unroll
                    for (int r = 0; r < 16; ++r) {
                        int kvr = kv0 + t * 32 + (r & 3) + 8 * (r >> 2) + 4 * hi;
                        if (kvr > qg) s[t][r] = NEG_SENTINEL;
                    }
            }
            // row max: in-register tree + one cross-half exchange
            float red[16];
#pragma unroll
            for (int i = 0; i < 16; ++i) red[i] = fmaxf(s[0][i], s[1][i]);
#pragma unroll
            for (int w = 8; w >= 1; w >>= 1)
#pragma unroll
                for (int i = 0; i < w; ++i) red[i] = fmaxf(red[i], red[i + w]);
            float pmax = fmaxf(red[0], __shfl_xor(red[0], 32));
            // defer-max (T13): rescale only when max grew past threshold
            if (!__all(pmax - m_i <= 8.f)) {
                float mnew  = fmaxf(m_i, pmax);
                float alpha = exp2f(m_i - mnew);
                m_i = mnew;
                l_i *= alpha;
#pragma unroll
                for (int nb = 0; nb < 4; ++nb)
#pragma unroll
                    for (int r = 0; r < 16; ++r) o[nb][r] *= alpha;
            }
            // P = exp2(s - m), row sum (tree + one exchange)
            float sum[16];
#pragma unroll
            for (int i = 0; i < 16; ++i) {
                float p0 = exp2f(s[0][i] - m_i);
                float p1 = exp2f(s[1][i] - m_i);
                s[0][i] = p0; s[1][i] = p1;
                sum[i] = p0 + p1;
            }
#pragma unroll
            for (int w = 8; w >= 1; w >>= 1)
#pragma unroll
                for (int i = 0; i < w; ++i) sum[i] += sum[i + w];
            l_i += sum[0] + __shfl_xor(sum[0], 32);

            // P -> bf16 A-operand fragments (cvt_pk + permlane32_swap)
            bf16x8_t pa[4];
#pragma unroll
            for (int ks = 0; ks < 4; ++ks) {
                const int t = ks >> 1, u8 = (ks & 1) * 8;
                unsigned int a0 = cvtpk_bf16(s[t][u8 + 0], s[t][u8 + 1]);
                unsigned int a1 = cvtpk_bf16(s[t][u8 + 2], s[t][u8 + 3]);
                unsigned int b0 = cvtpk_bf16(s[t][u8 + 4], s[t][u8 + 5]);
                unsigned int b1 = cvtpk_bf16(s[t][u8 + 6], s[t][u8 + 7]);
                asm("v_permlane32_swap_b32 %0, %1" : "+v"(a0), "+v"(b0));
                asm("v_permlane32_swap_b32 %0, %1" : "+v"(a1), "+v"(b1));
                union { unsigned int w[4]; bf16x8_t v; } pk;
                pk.w[0] = a0; pk.w[1] = a1; pk.w[2] = b0; pk.w[3] = b1;
                pa[ks] = pk.v;
            }
            // O += P V : B-operand from Vs[d][kv]
#pragma unroll
            for (int ks = 0; ks < 4; ++ks) {
                const int col = ks * 16 + hi * 8;
#pragma unroll
                for (int nb = 0; nb < 4; ++nb) {
                    const int row = nb * 32 + l31;
                    bf16x8_t vb = *(const bf16x8_t*)(
                        &Vb[row * 64 + (col ^ kxor(row))]);
                    o[nb] = __builtin_amdgcn_mfma_f32_32x32x16_bf16(
                        pa[ks], vb, o[nb], 0, 0, 0);
                }
            }
        }
    }
    // epilogue: normalize rows; 1/l lives in lane (q = l31); rows need
    // lane crow(r,hi)'s value -> wave broadcast shfl
    float il = 1.f / l_i;
#pragma unroll
    for (int r = 0; r < 16; ++r) {
        const int crow = (r & 3) + 8 * (r >> 2) + 4 * hi;
        float ilr = __shfl(il, crow);
        const int s_idx = q0w + crow;
#pragma unroll
        for (int nb = 0; nb < 4; ++nb)
            ctx[((size_t)(b * S_ + s_idx) * H_ + h) * DH_ + nb * 32 + l31] =
                f2b(o[nb][r] * ilr);
    }
}

// ---------------------------------------------------------------------------
extern "C" void kernel_launch(void* const* d_in, const int* in_sizes, int n_in,
                              void* d_out, int out_size, void* d_ws, size_t ws_size,
                              hipStream_t stream) {
    const float* x  = (const float*)d_in[0];
    const float* Wq = (const float*)d_in[1];
    const float* Wk = (const float*)d_in[2];
    const float* Wv = (const float*)d_in[3];
    const float* Wo = (const float*)d_in[4];
    // d_in[5] = mask (unused; causal computed analytically)

    float* out    = (float*)d_out;                           // [B][S][H*DH]  8,388,608 f32
    float* kc_out = out + (size_t)B_ * S_ * H_ * DH_;        // [B][G][S][DH] 2,097,152 f32
    float* vc_out = kc_out + (size_t)B_ * G_ * S_ * DH_;     // [B][G][S][DH] 2,097,152 f32

    // Borrow `out` f32 region (= 16M u16) as early scratch; both buffers are
    // dead before the final gemm writes `out` (single stream, serialized).
    u16* outw = (u16*)d_out;
    u16* xb   = outw;             // 8M u16, live phases 1-2 (x cast to bf16)
    u16* qraw = outw + 8388608;   // 8M u16, live phases 2-4

    // Workspace: 16M u16 = 32 MiB, phase-safe overlays
    u16* ws    = (u16*)d_ws;
    u16* WqT   = ws;              // 4M, phases 1-2
    u16* WoT   = ws;              // 4M, phases 3-5 (transposed after q-gemm)
    u16* WkvT  = ws + 4194304;    // 2M, phases 1-2
    u16* kb    = ws + 4194304;    // 2M, phases 3-4
    u16* vt    = ws + 6291456;    // 2M, phases 3-4
    u16* kvraw = ws + 8388608;    // 4M, phases 2-3
    u16* ctx   = ws + 8388608;    // 8M, phases 4-5

    dim3 blk(256);
    // phase 1: casts + W transposes
    cast_x<<<dim3(4096), blk, 0, stream>>>(x, xb);
    transpose_f32_bf16<<<dim3(64, 64), blk, 0, stream>>>(Wq, WqT, 2048, 2048);
    transpose_f32_bf16<<<dim3(16, 64), blk, 0, stream>>>(Wk, WkvT, 2048, 512);
    transpose_f32_bf16<<<dim3(16, 64), blk, 0, stream>>>(Wv, WkvT + (size_t)512 * 2048, 2048, 512);

    // phase 2: projections
    gemm_nt<u16><<<dim3(16, 32), blk, 0, stream>>>(xb, WqT, qraw, 4096, 2048, 2048);
    gemm_nt<u16><<<dim3(8, 32),  blk, 0, stream>>>(xb, WkvT, kvraw, 4096, 1024, 2048);

    // phase 3: RoPE + cache outputs (+ Wo transpose into WqT's slot)
    transpose_f32_bf16<<<dim3(64, 64), blk, 0, stream>>>(Wo, WoT, 2048, 2048);
    rope_q<<<dim3(16384), blk, 0, stream>>>(qraw);
    k_prep<<<dim3(4096),  blk, 0, stream>>>(kvraw, kc_out, kb);
    v_prep<<<dim3(64, 4, 8), blk, 0, stream>>>(kvraw, vc_out, vt);

    // phase 4: attention (split pairs -> 2 blocks/CU, lockstep kv sweep)
    flash_attn<<<dim3(512), blk, 0, stream>>>(qraw, kb, vt, ctx);

    // phase 5: output projection (f32 out)
    gemm_nt<float><<<dim3(16, 32), blk, 0, stream>>>(ctx, WoT, out, 4096, 2048, 2048);
}